// Round 1
// baseline (185.655 us; speedup 1.0000x reference)
//
#include <hip/hip_runtime.h>

// 5x5 mean filter, count_include_pad=False, on [32,3,512,512] fp32.
// Separable box sums; one wave per (plane, 32-row strip); lane owns 8 cols.

#define HH 512
#define WW 512
#define NPLANES 96      // B*C = 32*3
#define SROWS 32        // output rows per wave
#define STRIPS (HH / SROWS)

__global__ __launch_bounds__(64, 4) void box5_kernel(const float* __restrict__ x,
                                                     float* __restrict__ out) {
    const int lane = threadIdx.x;            // 0..63
    const int gid = blockIdx.x;              // one wave per block
    const int plane = gid / STRIPS;
    const int strip = gid % STRIPS;
    const int y0 = strip * SROWS;
    const int ylast = y0 + SROWS + 1;        // last input row we consume

    const float* px = x + (size_t)plane * (HH * WW);
    float* pout = out + (size_t)plane * (HH * WW);

    const int w0 = lane * 8;

    // Per-column inverse counts (boundary-aware), constant per thread.
    float inv_cw[8];
#pragma unroll
    for (int j = 0; j < 8; ++j) {
        int w = w0 + j;
        int cw = min(w + 2, WW - 1) - max(w - 2, 0) + 1;
        inv_cw[j] = 1.0f / (float)cw;
    }

    // History of horizontal sums for the last 5 input rows (zero = OOB row).
    float h[5][8];
#pragma unroll
    for (int r = 0; r < 5; ++r)
#pragma unroll
        for (int j = 0; j < 8; ++j) h[r][j] = 0.0f;

    // Row pointer with vertical clamp (mask applied later, so clamped loads
    // are harmless and keep all lanes converged).
    auto rowptr = [&](int y) {
        int yc = min(max(y, 0), HH - 1);
        return px + (size_t)yc * WW + w0;
    };

    // Depth-2 software pipeline: two rows in flight.
    float4 a0, b0, a1, b1;
    {
        const float* p = rowptr(y0 - 2);
        a0 = *(const float4*)(p);
        b0 = *(const float4*)(p + 4);
        p = rowptr(y0 - 1);
        a1 = *(const float4*)(p);
        b1 = *(const float4*)(p + 4);
    }

    for (int y_in = y0 - 2; y_in <= ylast; ++y_in) {
        // Issue prefetch of row y_in+2 (clamped into our strip's range so the
        // tail prefetches are L1 hits, not fresh HBM lines).
        float4 a2, b2;
        {
            int yp = y_in + 2;
            if (yp > ylast) yp = ylast;
            const float* p = rowptr(yp);
            a2 = *(const float4*)(p);
            b2 = *(const float4*)(p + 4);
        }

        // ---- process current row (a0,b0) = input row y_in ----
        float xv0 = a0.x, xv1 = a0.y, xv2 = a0.z, xv3 = a0.w;
        float xv4 = b0.x, xv5 = b0.y, xv6 = b0.z, xv7 = b0.w;

        // Horizontal halo from neighbor lanes.
        float xm2 = __shfl_up(xv6, 1);
        float xm1 = __shfl_up(xv7, 1);
        float xp1 = __shfl_down(xv0, 1);
        float xp2 = __shfl_down(xv1, 1);
        if (lane == 0)  { xm2 = 0.0f; xm1 = 0.0f; }
        if (lane == 63) { xp1 = 0.0f; xp2 = 0.0f; }

        const float mask = (y_in >= 0 && y_in < HH) ? 1.0f : 0.0f;

        // Sliding 5-tap horizontal sums for our 8 columns.
        float hn[8];
        float t = xm2 + xm1 + xv0 + xv1 + xv2;
        hn[0] = t;
        t += xv3 - xm2; hn[1] = t;
        t += xv4 - xm1; hn[2] = t;
        t += xv5 - xv0; hn[3] = t;
        t += xv6 - xv1; hn[4] = t;
        t += xv7 - xv2; hn[5] = t;
        t += xp1 - xv3; hn[6] = t;
        t += xp2 - xv4; hn[7] = t;
#pragma unroll
        for (int j = 0; j < 8; ++j) hn[j] *= mask;

        // Shift vertical history, append new row.
#pragma unroll
        for (int r = 0; r < 4; ++r)
#pragma unroll
            for (int j = 0; j < 8; ++j) h[r][j] = h[r + 1][j];
#pragma unroll
        for (int j = 0; j < 8; ++j) h[4][j] = hn[j];

        // Emit output row y_out = y_in - 2 once its full window is in history.
        const int y_out = y_in - 2;
        if (y_out >= y0 && y_out < y0 + SROWS) {
            int ch = min(y_out + 2, HH - 1) - max(y_out - 2, 0) + 1;
            float inv_ch = 1.0f / (float)ch;   // wave-uniform
            float o[8];
#pragma unroll
            for (int j = 0; j < 8; ++j) {
                float vs = h[0][j] + h[1][j] + h[2][j] + h[3][j] + h[4][j];
                o[j] = vs * (inv_cw[j] * inv_ch);
            }
            float* po = pout + (size_t)y_out * WW + w0;
            *(float4*)(po)     = make_float4(o[0], o[1], o[2], o[3]);
            *(float4*)(po + 4) = make_float4(o[4], o[5], o[6], o[7]);
        }

        // Rotate pipeline registers.
        a0 = a1; b0 = b1; a1 = a2; b1 = b2;
    }
}

extern "C" void kernel_launch(void* const* d_in, const int* in_sizes, int n_in,
                              void* d_out, int out_size, void* d_ws, size_t ws_size,
                              hipStream_t stream) {
    const float* x = (const float*)d_in[0];
    float* out = (float*)d_out;
    // k_size (d_in[1]) is fixed at 5 per the reference; hard-coded above.
    dim3 grid(NPLANES * STRIPS);
    box5_kernel<<<grid, 64, 0, stream>>>(x, out);
}